// Round 8
// baseline (159.468 us; speedup 1.0000x reference)
//
#include <hip/hip_runtime.h>
#include <math.h>

typedef _Float16 f16;
typedef _Float16 f16x2 __attribute__((ext_vector_type(2)));
typedef _Float16 f16x4 __attribute__((ext_vector_type(4)));
typedef _Float16 f16x8 __attribute__((ext_vector_type(8)));
typedef float    f32x4 __attribute__((ext_vector_type(4)));
typedef float    f32x16 __attribute__((ext_vector_type(16)));

#define NB 4096
#define LT 512
#define NC 16
#define NS 32

// workspace layout (bytes)
#define WS_P0     0                     // 32 f32, softmax(init)*256
#define WS_SIG    128                   // 32 f32, sigmoid(acc)*256
#define WS_SUMSIG 256                   // 1 f32
#define WS_FWDT   512                   // 16384 f16 = 32768 B
#define WS_BWDT   (512 + 32768)
#define WS_F      (512 + 65536)         // 32*4096 f32
#define WS_G      (WS_F + 32*4096*4)

#if __has_builtin(__builtin_amdgcn_exp2f)
#define EXP2F __builtin_amdgcn_exp2f
#else
#define EXP2F exp2f
#endif

// ---------------- prep: softmaxes + per-state fp16 transition slices ----------
// Slice ks (0..31) = one state; its 16 k-rows = the 16 symbols c, row-half = c-half.
// fwd: slice state = source p (broadcast p[p']); A rows m = n'. A[m=n][k=(ht,j)] = T[p=ks][c=8ht+j][n]
// bwd: slice state = dest  n (broadcast g[n]);  A rows m = p.  A[m=p][k=(ht,j)] = T[p][c=8ht+j][n=ks]
__global__ __launch_bounds__(512) void pdfa_prep(const float* __restrict__ tlogit,
                                                 const float* __restrict__ ilogit,
                                                 const float* __restrict__ alogit,
                                                 char* __restrict__ ws) {
    int tid = threadIdx.x;           // 512 threads = one (p,c) row each
    f16* fwdT = (f16*)(ws + WS_FWDT);
    f16* bwdT = (f16*)(ws + WS_BWDT);
    int p = tid >> 4, c = tid & 15;
    const float* row = tlogit + p * 512 + c * 32;
    float mx = row[0];
    for (int n = 1; n < 32; ++n) mx = fmaxf(mx, row[n]);
    float s = 0.f;
    for (int n = 0; n < 32; ++n) s += expf(row[n] - mx);
    float inv = 1.f / s;
    int ht = c >> 3, j = c & 7;
    for (int n = 0; n < 32; ++n) {
        float tv = expf(row[n] - mx) * inv;
        fwdT[p * 512 + (32 * ht + n) * 8 + j] = (f16)tv;   // lane = 32*ht + n
        bwdT[n * 512 + (32 * ht + p) * 8 + j] = (f16)tv;   // lane = 32*ht + p
    }
    if (tid < 32) {
        float m0 = ilogit[0];
        for (int n = 1; n < 32; ++n) m0 = fmaxf(m0, ilogit[n]);
        float s0 = 0.f;
        for (int n = 0; n < 32; ++n) s0 += expf(ilogit[n] - m0);
        ((float*)(ws + WS_P0))[tid]  = 256.f * expf(ilogit[tid] - m0) / s0;
        ((float*)(ws + WS_SIG))[tid] = 256.f / (1.f + expf(-alogit[tid]));
    }
    if (tid == 0) {
        float ss = 0.f;
        for (int n = 0; n < 32; ++n) ss += 1.f / (1.f + expf(-alogit[n]));
        *(float*)(ws + WS_SUMSIG) = ss;
    }
}

// ---------------- main: K-split-8, shared-x-hat production, 256 blocks --------
#define EC(v) ((f16)EXP2F((v) * 1.44269504089f))

// one slice: broadcast state scalar pnew[M], 4 pk_mul on the shared x-hat vec
#define KS(M, ACC, CIN) { \
    f16 pv_ = pnew[M]; \
    f16x8 pb_ = {pv_, pv_, pv_, pv_, pv_, pv_, pv_, pv_}; \
    f16x8 bf_ = pb_ * xq8; \
    ACC = __builtin_amdgcn_mfma_f32_32x32x16_f16(af[M], bf_, CIN, 0, 0, 0); }

// one time-step (phase P): 4 MFMA (2 accs), f16 partial -> LDS, produce ONE
// x-hat value for step s+1 into xbuf[P^1], issue global load for t(s+2),
// barrier, read 8 partials of own 4 states + next x-hat f16x8, pk_add tree.
#define STEP(P, XRAW, TNEXT) { \
    f32x16 a0_, a1_; \
    __builtin_amdgcn_s_setprio(1); \
    KS(0, a0_, z) KS(1, a1_, z) \
    KS(2, a0_, a0_) KS(3, a1_, a1_) \
    __builtin_amdgcn_s_setprio(0); \
    f32x16 pf_ = a0_ + a1_; \
    char* wb_ = lds_pw + (P) * 18432; \
    *(f16x4*)(wb_ + 0  + 8*hi) = f16x4{(f16)pf_[0],  (f16)pf_[1],  (f16)pf_[2],  (f16)pf_[3]};  \
    *(f16x4*)(wb_ + 16 + 8*hi) = f16x4{(f16)pf_[4],  (f16)pf_[5],  (f16)pf_[6],  (f16)pf_[7]};  \
    *(f16x4*)(wb_ + 32 + 8*hi) = f16x4{(f16)pf_[8],  (f16)pf_[9],  (f16)pf_[10], (f16)pf_[11]}; \
    *(f16x4*)(wb_ + 48 + 8*hi) = f16x4{(f16)pf_[12], (f16)pf_[13], (f16)pf_[14], (f16)pf_[15]}; \
    *(f16*)(lds_xw + (((P)^1) * 1280)) = EC(XRAW); \
    XRAW = xg[(size_t)(TNEXT) * NC]; \
    __syncthreads(); \
    const char* rb_ = lds_pr + (P) * 18432; \
    f16x4 q0_ = *(const f16x4*)(rb_); \
    f16x4 q1_ = *(const f16x4*)(rb_ + 1 * 2304); \
    f16x4 q2_ = *(const f16x4*)(rb_ + 2 * 2304); \
    f16x4 q3_ = *(const f16x4*)(rb_ + 3 * 2304); \
    f16x4 q4_ = *(const f16x4*)(rb_ + 4 * 2304); \
    f16x4 q5_ = *(const f16x4*)(rb_ + 5 * 2304); \
    f16x4 q6_ = *(const f16x4*)(rb_ + 6 * 2304); \
    f16x4 q7_ = *(const f16x4*)(rb_ + 7 * 2304); \
    xq8 = *(const f16x8*)(lds_xr + (((P)^1) * 1280)); \
    pnew = ((q0_ + q1_) + (q2_ + q3_)) + ((q4_ + q5_) + (q6_ + q7_)); }

__global__ __launch_bounds__(512, 1) void pdfa_main(const float* __restrict__ login,
                                                    char* __restrict__ ws) {
    // partials: [buf 2][wave 8][br 32][row 72 B] = 36 KB; xbuf: [buf 2][br 32][40 B] = 2.5 KB
    __shared__ __align__(16) char partb[2 * 18432 + 2 * 1280];
    const int tid  = threadIdx.x;
    const int w    = tid >> 6;              // 0..7: wave = state-group (states 4w..4w+3)
    const int lane = tid & 63;
    const int br   = tid & 31;
    const int hi   = (tid >> 5) & 1;
    const int bid  = blockIdx.x;
    const int dir  = bid & 1;               // 0 = fwd (t 0..255), 1 = bwd (t 511..256)
    const int b0   = (bid >> 1) << 5;

    // this wave's 4 A-slices (states 4w+m), 4 x 16B = 16 VGPRs
    const char* tblb = ws + (dir ? WS_BWDT : WS_FWDT);
    f16x8 af[4];
#pragma unroll
    for (int m = 0; m < 4; ++m)
        af[m] = *(const f16x8*)(tblb + (4 * w + m) * 1024 + lane * 16);

    // running state: own 4 states (4w..4w+3)
    const float* initv = (const float*)(ws + (dir ? WS_SIG : WS_P0));
    f16x4 pnew;
#pragma unroll
    for (int j = 0; j < 4; ++j) pnew[j] = (f16)initv[4 * w + j];

    // LDS pointers
    char* lds_pw = &partb[0] + w * 2304 + br * 72;          // partial write base
    const char* lds_pr = &partb[0] + br * 72 + 8 * w;       // partial read base
    char* xbase_lds = &partb[0] + 2 * 18432;
    char* lds_xw = xbase_lds + br * 40 + (8 * hi + w) * 2;  // x-hat write (1 f16)
    const char* lds_xr = xbase_lds + br * 40 + hi * 16;     // x-hat read (f16x8)

    // global x: this wave-lane's single c-value stream, c = 8*hi + w
    const float* xg = login + (size_t)(b0 + br) * (LT * NC) + 8 * hi + w;

    const f32x16 z{};
    f16x8 xq8;
    float xrA, xrB;

#define TT(S) (dir ? (511 - (S)) : (S))
    xrA = xg[(size_t)TT(0) * NC];
    xrB = xg[(size_t)TT(1) * NC];
    *(f16*)(lds_xw) = EC(xrA);              // xbuf[0] = x-hat(t0)
    xrA = xg[(size_t)TT(2) * NC];           // A now prefetches t2
    __syncthreads();
    xq8 = *(const f16x8*)(lds_xr);

    for (int s = 0; s < 256; s += 2) {
        STEP(0, xrB, TT(s + 3))             // uses x-hat(s), produces x-hat(s+1) from xrB, loads t(s+3)
        STEP(1, xrA, TT(s + 4))             // uses x-hat(s+1), produces x-hat(s+2) from xrA, loads t(s+4)
    }
#undef TT

    // final p (states 4w..4w+3, col br) -> f or g, laid out [state][b]
    if (hi == 0) {
        float* outv = (float*)(ws + (dir ? WS_G : WS_F));
#pragma unroll
        for (int j = 0; j < 4; ++j)
            outv[(size_t)(4 * w + j) * NB + b0 + br] = (float)pnew[j];
    }
}

// ---------------- combine: out[b] = log( f.g / 65536 + 1e-20*sum(sigma) ) ------
__global__ __launch_bounds__(256) void pdfa_combine(const char* __restrict__ ws,
                                                    float* __restrict__ out) {
    int b = blockIdx.x * 256 + threadIdx.x;
    const float* f = (const float*)(ws + WS_F);
    const float* g = (const float*)(ws + WS_G);
    float ss = *(const float*)(ws + WS_SUMSIG);
    float dot = 0.f;
#pragma unroll
    for (int s2 = 0; s2 < 32; ++s2)
        dot = fmaf(f[s2 * NB + b], g[s2 * NB + b], dot);
    out[b] = logf(dot * (1.f / 65536.f) + 1e-20f * ss);
}

extern "C" void kernel_launch(void* const* d_in, const int* in_sizes, int n_in,
                              void* d_out, int out_size, void* d_ws, size_t ws_size,
                              hipStream_t stream) {
    const float* login = (const float*)d_in[0];
    const float* ilog  = (const float*)d_in[1];
    const float* tlog  = (const float*)d_in[2];
    const float* alog  = (const float*)d_in[3];
    char* ws = (char*)d_ws;

    pdfa_prep<<<1, 512, 0, stream>>>(tlog, ilog, alog, ws);
    pdfa_main<<<256, 512, 0, stream>>>(login, ws);
    pdfa_combine<<<NB / 256, 256, 0, stream>>>(ws, (float*)d_out);
}

// Round 9
// 143.224 us; speedup vs baseline: 1.1134x; 1.1134x over previous
//
#include <hip/hip_runtime.h>
#include <math.h>

typedef _Float16 f16;
typedef _Float16 f16x2 __attribute__((ext_vector_type(2)));
typedef _Float16 f16x4 __attribute__((ext_vector_type(4)));
typedef _Float16 f16x8 __attribute__((ext_vector_type(8)));
typedef float    f32x4 __attribute__((ext_vector_type(4)));

#define NB 4096
#define LT 512
#define NC 16
#define NS 32

// workspace layout (bytes)
#define WS_P0     0                     // 32 f32, softmax(init)*256
#define WS_SIG    128                   // 32 f32, sigmoid(acc)*256
#define WS_SUMSIG 256                   // 1 f32
#define WS_FWDT   512                   // 16384 f16 = 32768 B
#define WS_BWDT   (512 + 32768)
#define WS_F      (512 + 65536)         // 32*4096 f32
#define WS_G      (WS_F + 32*4096*4)

#if __has_builtin(__builtin_amdgcn_exp2f)
#define EXP2F __builtin_amdgcn_exp2f
#else
#define EXP2F exp2f
#endif

// ---------------- prep: softmaxes + fragment tables for 16x16x32 MFMA ---------
// Wave w owns source states {4w..4w+3} = 2 k-chunks (kc) of 32 k-slots.
// k-slot in chunk = 8g + j: g = 2*sp + chalf (sp = source-state LSB, via lane>>5
// on the B side), c = 8*chalf + j. Two row-half MFMAs r (rows 16r..16r+15).
// A-frag convention (16x16x32): A[m = lane&15][k = 8*(lane>>4) + j].
// fwd: source = p, rows = n.   bwd: source = n, rows = p.
__global__ __launch_bounds__(512) void pdfa_prep(const float* __restrict__ tlogit,
                                                 const float* __restrict__ ilogit,
                                                 const float* __restrict__ alogit,
                                                 char* __restrict__ ws) {
    int tid = threadIdx.x;           // 512 threads = one (p,c) row each
    f16* fwdT = (f16*)(ws + WS_FWDT);
    f16* bwdT = (f16*)(ws + WS_BWDT);
    int p = tid >> 4, c = tid & 15;
    const float* row = tlogit + p * 512 + c * 32;
    float mx = row[0];
    for (int n = 1; n < 32; ++n) mx = fmaxf(mx, row[n]);
    float s = 0.f;
    for (int n = 0; n < 32; ++n) s += expf(row[n] - mx);
    float inv = 1.f / s;
    int chalf = c >> 3, j = c & 7;
    for (int n = 0; n < 32; ++n) {
        float tv = expf(row[n] - mx) * inv;
        // fwd: w=p>>2, kc=(p>>1)&1, g=2*(p&1)+chalf, r=n>>4, m=n&15
        fwdT[((((p >> 2) * 2 + ((p >> 1) & 1)) * 2 + (n >> 4)) * 64
              + 16 * (2 * (p & 1) + chalf) + (n & 15)) * 8 + j] = (f16)tv;
        // bwd: w=n>>2, kc=(n>>1)&1, g=2*(n&1)+chalf, r=p>>4, m=p&15
        bwdT[((((n >> 2) * 2 + ((n >> 1) & 1)) * 2 + (p >> 4)) * 64
              + 16 * (2 * (n & 1) + chalf) + (p & 15)) * 8 + j] = (f16)tv;
    }
    if (tid < 32) {
        float m0 = ilogit[0];
        for (int n = 1; n < 32; ++n) m0 = fmaxf(m0, ilogit[n]);
        float s0 = 0.f;
        for (int n = 0; n < 32; ++n) s0 += expf(ilogit[n] - m0);
        ((float*)(ws + WS_P0))[tid]  = 256.f * expf(ilogit[tid] - m0) / s0;
        ((float*)(ws + WS_SIG))[tid] = 256.f / (1.f + expf(-alogit[tid]));
    }
    if (tid == 0) {
        float ss = 0.f;
        for (int n = 0; n < 32; ++n) ss += 1.f / (1.f + expf(-alogit[n]));
        *(float*)(ws + WS_SUMSIG) = ss;
    }
}

// ---------------- main: 512 chains (16-col tiles), 2 blocks/CU, K-split-8 -----
#define EC(v) ((f16)EXP2F((v) * 1.44269504089f))

#define XBUF_OFF 16384
// LDS: [0,8192) partials buf0, [8192,16384) buf1,
//      [16384,+768) xbuf0, [+768,+1536) xbuf1.  total 17920 B

// one time-step (phase P): build 2 B-frags, 4 MFMA (2 dep-chains of 2),
// f16 partials -> LDS, produce one x-hat value (waves 0-3) + issue next load,
// barrier, read 8 partials + next x-hat, pk_add tree.
#define STEP(P, XRAW, TNEXT) { \
    f16 p0_ = h32 ? pnew[1] : pnew[0]; \
    f16 p1_ = h32 ? pnew[3] : pnew[2]; \
    f16x8 pb0_ = {p0_, p0_, p0_, p0_, p0_, p0_, p0_, p0_}; \
    f16x8 pb1_ = {p1_, p1_, p1_, p1_, p1_, p1_, p1_, p1_}; \
    f16x8 b0_ = pb0_ * xq8; \
    f16x8 b1_ = pb1_ * xq8; \
    __builtin_amdgcn_s_setprio(1); \
    f32x4 aR0_ = __builtin_amdgcn_mfma_f32_16x16x32_f16(af[0][0], b0_, z4, 0, 0, 0); \
    f32x4 aR1_ = __builtin_amdgcn_mfma_f32_16x16x32_f16(af[1][0], b0_, z4, 0, 0, 0); \
    aR0_ = __builtin_amdgcn_mfma_f32_16x16x32_f16(af[0][1], b1_, aR0_, 0, 0, 0); \
    aR1_ = __builtin_amdgcn_mfma_f32_16x16x32_f16(af[1][1], b1_, aR1_, 0, 0, 0); \
    __builtin_amdgcn_s_setprio(0); \
    char* wp_ = lds + (P) * 8192 + w * 1024 + lane * 8; \
    *(f16x4*)(wp_)       = f16x4{(f16)aR0_[0], (f16)aR0_[1], (f16)aR0_[2], (f16)aR0_[3]}; \
    *(f16x4*)(wp_ + 512) = f16x4{(f16)aR1_[0], (f16)aR1_[1], (f16)aR1_[2], (f16)aR1_[3]}; \
    if (produce) { \
        *(f16*)(xw + (((P)^1)) * 768) = EC(XRAW); \
        XRAW = xg[(size_t)(TNEXT) * NC]; \
    } \
    __syncthreads(); \
    const char* rp_ = lds + (P) * 8192 + (w >> 2) * 512 + (w & 3) * 128 + col * 8; \
    f16x4 q0_ = *(const f16x4*)(rp_); \
    f16x4 q1_ = *(const f16x4*)(rp_ + 1024); \
    f16x4 q2_ = *(const f16x4*)(rp_ + 2048); \
    f16x4 q3_ = *(const f16x4*)(rp_ + 3072); \
    f16x4 q4_ = *(const f16x4*)(rp_ + 4096); \
    f16x4 q5_ = *(const f16x4*)(rp_ + 5120); \
    f16x4 q6_ = *(const f16x4*)(rp_ + 6144); \
    f16x4 q7_ = *(const f16x4*)(rp_ + 7168); \
    xq8 = *(const f16x8*)(xr_base + (((P)^1)) * 768); \
    pnew = ((q0_ + q1_) + (q2_ + q3_)) + ((q4_ + q5_) + (q6_ + q7_)); }

__global__ __launch_bounds__(512, 4) void pdfa_main(const float* __restrict__ login,
                                                    char* __restrict__ ws) {
    __shared__ __align__(16) char lds[2 * 8192 + 2 * 768];
    const int tid  = threadIdx.x;
    const int w    = tid >> 6;              // 0..7: wave = source-state group (4w..4w+3)
    const int lane = tid & 63;
    const int col  = lane & 15;             // batch column within 16-wide tile
    const int chalf = (lane >> 4) & 1;
    const int h32  = lane >> 5;             // selects state LSB within k-chunk
    const int bid  = blockIdx.x;
    const int dir  = bid & 1;               // 0 = fwd (t 0..255), 1 = bwd (t 511..256)
    const int b0   = (bid >> 1) << 4;

    // this wave's 4 A-frags [r][kc], 4 x 16B = 16 VGPRs
    const char* tblb = ws + (dir ? WS_BWDT : WS_FWDT);
    f16x8 af[2][2];
#pragma unroll
    for (int r = 0; r < 2; ++r)
#pragma unroll
        for (int kc = 0; kc < 2; ++kc)
            af[r][kc] = *(const f16x8*)(tblb + (((w * 2 + kc) * 2 + r) * 64 + lane) * 16);

    // running state: own 4 source states (4w..4w+3), value for column `col`
    const float* initv = (const float*)(ws + (dir ? WS_SIG : WS_P0));
    f16x4 pnew;
#pragma unroll
    for (int j = 0; j < 4; ++j) pnew[j] = (f16)initv[4 * w + j];

    // x-hat producer: waves 0-3, one (colv, cv) value per lane per step
    const bool produce = (tid < 256);
    const int colv = (tid >> 4) & 15, cv = tid & 15;
    const float* xg = login + (size_t)(b0 + colv) * (LT * NC) + cv;
    char* xw = lds + XBUF_OFF + colv * 48 + (cv >> 3) * 16 + (cv & 7) * 2;
    const char* xr_base = lds + XBUF_OFF + col * 48 + chalf * 16;

    const f32x4 z4{};
    f16x8 xq8;
    float xrA = 0.f, xrB = 0.f;

#define TT(S) (dir ? (511 - (S)) : (S))
    if (produce) {
        xrA = xg[(size_t)TT(0) * NC];
        xrB = xg[(size_t)TT(1) * NC];
        *(f16*)(xw) = EC(xrA);              // xbuf0 = x-hat(t0)
        xrA = xg[(size_t)TT(2) * NC];       // A now prefetches t2
    }
    __syncthreads();
    xq8 = *(const f16x8*)(xr_base);

    for (int s = 0; s < 256; s += 2) {
        STEP(0, xrB, TT(s + 3))             // uses x-hat(s); produces x-hat(s+1); loads t(s+3)
        STEP(1, xrA, TT(s + 4))             // uses x-hat(s+1); produces x-hat(s+2); loads t(s+4)
    }
#undef TT

    // final p (states 4w..4w+3, col) -> f or g, laid out [state][b]
    if (lane < 16) {
        float* outv = (float*)(ws + (dir ? WS_G : WS_F));
#pragma unroll
        for (int j = 0; j < 4; ++j)
            outv[(size_t)(4 * w + j) * NB + b0 + col] = (float)pnew[j];
    }
}

// ---------------- combine: out[b] = log( f.g / 65536 + 1e-20*sum(sigma) ) ------
__global__ __launch_bounds__(256) void pdfa_combine(const char* __restrict__ ws,
                                                    float* __restrict__ out) {
    int b = blockIdx.x * 256 + threadIdx.x;
    const float* f = (const float*)(ws + WS_F);
    const float* g = (const float*)(ws + WS_G);
    float ss = *(const float*)(ws + WS_SUMSIG);
    float dot = 0.f;
#pragma unroll
    for (int s2 = 0; s2 < 32; ++s2)
        dot = fmaf(f[s2 * NB + b], g[s2 * NB + b], dot);
    out[b] = logf(dot * (1.f / 65536.f) + 1e-20f * ss);
}

extern "C" void kernel_launch(void* const* d_in, const int* in_sizes, int n_in,
                              void* d_out, int out_size, void* d_ws, size_t ws_size,
                              hipStream_t stream) {
    const float* login = (const float*)d_in[0];
    const float* ilog  = (const float*)d_in[1];
    const float* tlog  = (const float*)d_in[2];
    const float* alog  = (const float*)d_in[3];
    char* ws = (char*)d_ws;

    pdfa_prep<<<1, 512, 0, stream>>>(tlog, ilog, alog, ws);
    pdfa_main<<<512, 512, 0, stream>>>(login, ws);
    pdfa_combine<<<NB / 256, 256, 0, stream>>>(ws, (float*)d_out);
}